// Round 17
// baseline (80.837 us; speedup 1.0000x reference)
//
#include <hip/hip_runtime.h>
#include <math.h>

#define B_    4
#define TDEC  512
#define TENC  1024
#define H_    128
#define DT    4

typedef float f2 __attribute__((ext_vector_type(2)));

// exp(2*enc) transposed, fp16-packed: [b][gp:16][e:1024][j:8]
__device__ _Float16 g_ebp[(size_t)B_ * 16 * TENC * 8];   // 1 MB
// enc transposed fp16: [b][h][e]  (contiguous e for the context phase)
__device__ _Float16 g_encht[(size_t)B_ * H_ * TENC];     // 1 MB
// per (row-tile rt, g): [V4(4), h-major ea pairs] = 20 f
__device__ float g_eav[(size_t)B_ * 128 * 32 * 20];      // 1.3 MB
__device__ float g_sv[1];                                // sum(V_w)

struct EAVP { float4 v4; f2 hd[8]; };
union F4 { float4 v; float f[4]; };
union H8 { float4 v; _Float16 h[8]; };
union H4 { ushort4 u4; _Float16 h[4]; };

static __device__ __forceinline__ f2 bc(float x) { f2 r = {x, x}; return r; }

// z<4: transpose enc -> fp16 exp(2*enc) planes + fp16 enc^T.  z==4: Ea+V pack.
__global__ __launch_bounds__(256) void prep_kernel(const float* __restrict__ enc,
                                                   const float* __restrict__ dec,
                                                   const float* __restrict__ Ww,
                                                   const float* __restrict__ Wb,
                                                   const float* __restrict__ Vw) {
    const int z = blockIdx.z;
    const int tx = threadIdx.x, ty = threadIdx.y;
    if (z < B_) {
        __shared__ float tile[32][33];               // [e-local][h-local]
        const int e0 = blockIdx.x * 32, h0 = blockIdx.y * 32, b = z;
        const float* ep = enc + (size_t)b * TENC * H_;
        #pragma unroll
        for (int j = 0; j < 32; j += 8)
            tile[ty + j][tx] = ep[(size_t)(e0 + ty + j) * H_ + h0 + tx];
        __syncthreads();
        const int g = (h0 >> 2) + ty, e = e0 + tx;
        const int gp = g >> 1, hs = g & 1;
        H4 o;
        // clamp below fp16 inf to avoid inf -> NaN in the rcp chain
        o.h[0] = (_Float16)fminf(__expf(2.f * tile[tx][4 * ty + 0]), 60000.f);
        o.h[1] = (_Float16)fminf(__expf(2.f * tile[tx][4 * ty + 1]), 60000.f);
        o.h[2] = (_Float16)fminf(__expf(2.f * tile[tx][4 * ty + 2]), 60000.f);
        o.h[3] = (_Float16)fminf(__expf(2.f * tile[tx][4 * ty + 3]), 60000.f);
        *(ushort4*)&g_ebp[((((size_t)b * 16 + gp) * TENC) + e) * 8 + hs * 4] = o.u4;
        // enc^T fp16 rows (coalesced in e across lanes)
        #pragma unroll
        for (int k = 0; k < 4; ++k)
            g_encht[((size_t)b * H_ + (h0 + 4 * ty + k)) * TENC + e]
                = (_Float16)tile[tx][4 * ty + k];
    } else {
        // 128 blocks x 16 rows: Ea = exp(2*(dec @ Ww^T + Wb)); pack Ea & V
        __shared__ float ds[16][H_];
        const int t = ty * 32 + tx;
        const int blk = blockIdx.y * 32 + blockIdx.x;      // 0..127
        const int R0 = blk * 16;
        #pragma unroll
        for (int i = 0; i < 8; ++i) {
            const int f = t + 256 * i;
            ds[f >> 7][f & 127] = dec[(size_t)R0 * H_ + f];
        }
        __syncthreads();
        const int k = t & 127, dd = t >> 7;
        const float* wr = Ww + (size_t)k * H_;
        float s[8];
        #pragma unroll
        for (int j = 0; j < 8; ++j) s[j] = 0.f;
        for (int h = 0; h < H_; h += 4) {
            const float4 w4 = *(const float4*)(wr + h);
            #pragma unroll
            for (int j = 0; j < 8; ++j) {
                const float4 d4 = *(const float4*)&ds[dd + 2 * j][h];
                s[j] = fmaf(w4.x, d4.x, s[j]);
                s[j] = fmaf(w4.y, d4.y, s[j]);
                s[j] = fmaf(w4.z, d4.z, s[j]);
                s[j] = fmaf(w4.w, d4.w, s[j]);
            }
        }
        const float wb = Wb[k], vw = Vw[k];
        const int g = k >> 2, jj = k & 3;
        #pragma unroll
        for (int j = 0; j < 8; ++j) {
            const int rl = dd + 2 * j;
            const int R = R0 + rl;
            const float ea = __expf(2.f * (s[j] + wb));
            // h-major, d-minor (packed d-pair math)
            g_eav[((size_t)(R >> 2) * 32 + g) * 20 + 4 + jj * 4 + (R & 3)] = ea;
        }
        if (dd == 0) {
            #pragma unroll
            for (int r = 0; r < 4; ++r)
                g_eav[((size_t)((R0 >> 2) + r) * 32 + g) * 20 + jj] = vw;
        }
        if (blk == 0) {
            __shared__ float svp[2];
            if (t < 128) {
                float x = vw;
                #pragma unroll
                for (int off = 32; off; off >>= 1) x += __shfl_xor(x, off);
                if ((t & 63) == 0) svp[t >> 6] = x;
            }
            __syncthreads();
            if (t == 0) g_sv[0] = svp[0] + svp[1];
        }
    }
}

// Packed 4-h fraction combine over a d-pair; one VOP3P op per step, 2 rcp.
__device__ __forceinline__ f2 term4p(f2 p0, f2 p1, f2 p2, f2 p3,
                                     const float4 v4, f2 acc) {
    const f2 q01 = p0 * p1, q23 = p2 * p3;
    const f2 a   = __builtin_elementwise_fma(bc(v4.y), p0, bc(v4.x) * p1);
    const f2 bq  = __builtin_elementwise_fma(bc(v4.w), p2, bc(v4.z) * p3);
    const f2 num = __builtin_elementwise_fma(bq, q01, a * q23);
    const f2 den = q01 * q23;
    f2 r;
    r.x = __builtin_amdgcn_rcpf(den.x);
    r.y = __builtin_amdgcn_rcpf(den.y);
    return __builtin_elementwise_fma(num, r, acc);
}

#define DALLP(S, t0, t1, t2, t3) do {                                          \
    const f2 one2 = {1.f, 1.f};                                                \
    f2 pA0 = __builtin_elementwise_fma(S.hd[0], bc(t0), one2);                 \
    f2 pB0 = __builtin_elementwise_fma(S.hd[1], bc(t0), one2);                 \
    f2 pA1 = __builtin_elementwise_fma(S.hd[2], bc(t1), one2);                 \
    f2 pB1 = __builtin_elementwise_fma(S.hd[3], bc(t1), one2);                 \
    f2 pA2 = __builtin_elementwise_fma(S.hd[4], bc(t2), one2);                 \
    f2 pB2 = __builtin_elementwise_fma(S.hd[5], bc(t2), one2);                 \
    f2 pA3 = __builtin_elementwise_fma(S.hd[6], bc(t3), one2);                 \
    f2 pB3 = __builtin_elementwise_fma(S.hd[7], bc(t3), one2);                 \
    acc01 = term4p(pA0, pA1, pA2, pA3, S.v4, acc01);                           \
    acc23 = term4p(pB0, pB1, pB2, pB3, S.v4, acc23);                           \
} while (0)

// Wave-private DMA staging: dest is wave-uniform; HW adds lane*16.
#define DMA16(ldst, gsrc)                                                      \
    __builtin_amdgcn_global_load_lds(                                          \
        (__attribute__((address_space(1))) void*)(gsrc),                       \
        (__attribute__((address_space(3))) void*)(ldst), 16, 0, 0)

// Fused: score + softmax(sum-only) + context + write.  Block = 1 row-tile,
// 1024 threads (1 e each); grid 512, XCD-swizzled.
// Phase 1: per-wave te double-buffer via global_load_lds + counted vmcnt —
// the ONLY VMEM ops in phase 1 are these DMAs, so the counts are sound.
__global__ __launch_bounds__(1024, 8) void fused_kernel(float* __restrict__ out) {
    __shared__ __align__(16) char shbuf[49424];
    float* sc    = (float*)shbuf;                 // [4][1024]      16 KB
    float* alias = (float*)(shbuf + 16384);       // tebuf[16][2][256] | part  32 KB
    float* wsum  = (float*)(shbuf + 49152);       // [16][4]
    float* rsum  = (float*)(shbuf + 49408);       // [4]

    const int t = threadIdx.x;
    const int w = t >> 6, lane = t & 63;
    const int bid = blockIdx.x;
    const int rt = (bid & 7) * 64 + (bid >> 3);   // XCD swizzle
    const int b = rt >> 7;
    const int R0 = rt * DT;
    const EAVP* epk = (const EAVP*)g_eav + (size_t)rt * 32;
    const _Float16* gte = g_ebp + (size_t)b * 16 * TENC * 8 + (size_t)t * 8;
    const float sv = g_sv[0];

    float* tbw = alias + w * 512;                 // this wave's 2x1KB buffers

    // --- Phase 1: scores ---
    DMA16(tbw + 0,   gte + 0 * (TENC * 8));
    DMA16(tbw + 256, gte + 1 * (TENC * 8));

    f2 acc01 = {0.f, 0.f}, acc23 = {0.f, 0.f};

    #pragma unroll
    for (int gp = 0; gp < 16; ++gp) {
        if (gp < 15) { asm volatile("s_waitcnt vmcnt(1)" ::: "memory"); }
        else         { asm volatile("s_waitcnt vmcnt(0)" ::: "memory"); }
        __builtin_amdgcn_sched_barrier(4);        // SALU may cross; VALU/DS/VMEM no
        H8 r;
        r.v = *(const float4*)(tbw + (gp & 1) * 256 + lane * 4);
        const float t0 = (float)r.h[0], t1 = (float)r.h[1];
        const float t2 = (float)r.h[2], t3 = (float)r.h[3];
        const float t4 = (float)r.h[4], t5 = (float)r.h[5];
        const float t6 = (float)r.h[6], t7 = (float)r.h[7];
        const EAVP A  = epk[2 * gp];
        const EAVP Bv = epk[2 * gp + 1];
        DALLP(A, t0, t1, t2, t3);
        DALLP(Bv, t4, t5, t6, t7);
        __builtin_amdgcn_sched_barrier(4);        // DMA must not hoist above compute
        if (gp < 14)
            DMA16(tbw + (gp & 1) * 256, gte + (size_t)(gp + 2) * (TENC * 8));
    }

    // --- Phase 2: p = exp(score); stash + per-wave partial sums ---
    const float q0 = __expf(fmaf(-2.f, acc01.x, sv));
    const float q1 = __expf(fmaf(-2.f, acc01.y, sv));
    const float q2 = __expf(fmaf(-2.f, acc23.x, sv));
    const float q3 = __expf(fmaf(-2.f, acc23.y, sv));
    sc[0 * TENC + t] = q0; sc[1 * TENC + t] = q1;
    sc[2 * TENC + t] = q2; sc[3 * TENC + t] = q3;

    float s0 = q0, s1 = q1, s2 = q2, s3 = q3;
    #pragma unroll
    for (int off = 32; off; off >>= 1) {
        s0 += __shfl_xor(s0, off);
        s1 += __shfl_xor(s1, off);
        s2 += __shfl_xor(s2, off);
        s3 += __shfl_xor(s3, off);
    }
    if (lane == 0) {
        wsum[w * 4 + 0] = s0; wsum[w * 4 + 1] = s1;
        wsum[w * 4 + 2] = s2; wsum[w * 4 + 3] = s3;
    }
    __syncthreads();
    if (t < 64) {                                 // lane = w'*4 + d
        float x = wsum[(t >> 2) * 4 + (t & 3)];
        #pragma unroll
        for (int off = 4; off < 64; off <<= 1) x += __shfl_xor(x, off);
        if (t < 4) rsum[t] = x;
    }

    // --- Phase 3: context partials; enc^T fp16, 16B loads; sc reads are
    //     wave-uniform broadcasts (q == w).  part[w] aliases THIS wave's tebuf.
    {
        const int q = w, h2 = lane;
        const _Float16* ebA = g_encht + ((size_t)b * H_ + 2 * h2) * TENC + q * 64;
        const _Float16* ebB = ebA + TENC;
        f2 a0 = {0.f, 0.f}, a1 = {0.f, 0.f}, a2 = {0.f, 0.f}, a3 = {0.f, 0.f};
        #pragma unroll
        for (int ee = 0; ee < 64; ee += 8) {
            H8 ra, rb;
            ra.v = *(const float4*)(ebA + ee);
            rb.v = *(const float4*)(ebB + ee);
            F4 u0a, u0b, u1a, u1b, u2a, u2b, u3a, u3b;
            u0a.v = *(const float4*)&sc[0 * TENC + q * 64 + ee];
            u0b.v = *(const float4*)&sc[0 * TENC + q * 64 + ee + 4];
            u1a.v = *(const float4*)&sc[1 * TENC + q * 64 + ee];
            u1b.v = *(const float4*)&sc[1 * TENC + q * 64 + ee + 4];
            u2a.v = *(const float4*)&sc[2 * TENC + q * 64 + ee];
            u2b.v = *(const float4*)&sc[2 * TENC + q * 64 + ee + 4];
            u3a.v = *(const float4*)&sc[3 * TENC + q * 64 + ee];
            u3b.v = *(const float4*)&sc[3 * TENC + q * 64 + ee + 4];
            #pragma unroll
            for (int j = 0; j < 4; ++j) {
                f2 ev; ev.x = (float)ra.h[j]; ev.y = (float)rb.h[j];
                a0 = __builtin_elementwise_fma(bc(u0a.f[j]), ev, a0);
                a1 = __builtin_elementwise_fma(bc(u1a.f[j]), ev, a1);
                a2 = __builtin_elementwise_fma(bc(u2a.f[j]), ev, a2);
                a3 = __builtin_elementwise_fma(bc(u3a.f[j]), ev, a3);
            }
            #pragma unroll
            for (int j = 0; j < 4; ++j) {
                f2 ev; ev.x = (float)ra.h[4 + j]; ev.y = (float)rb.h[4 + j];
                a0 = __builtin_elementwise_fma(bc(u0b.f[j]), ev, a0);
                a1 = __builtin_elementwise_fma(bc(u1b.f[j]), ev, a1);
                a2 = __builtin_elementwise_fma(bc(u2b.f[j]), ev, a2);
                a3 = __builtin_elementwise_fma(bc(u3b.f[j]), ev, a3);
            }
        }
        f2* part = (f2*)alias;                    // [16][4][64] f2
        part[q * 256 + 0 * 64 + h2] = a0;
        part[q * 256 + 1 * 64 + h2] = a1;
        part[q * 256 + 2 * 64 + h2] = a2;
        part[q * 256 + 3 * 64 + h2] = a3;
    }
    __syncthreads();

    // --- Phase 4: merge 16 slices, divide, write ---
    if (t < 256) {
        const int d = t >> 6, h2 = t & 63;
        const f2* part = (const f2*)alias;
        f2 s = {0.f, 0.f};
        #pragma unroll
        for (int q = 0; q < 16; ++q) s += part[q * 256 + d * 64 + h2];
        const float rinv = __builtin_amdgcn_rcpf(rsum[d]);
        s *= bc(rinv);
        *(f2*)(out + (size_t)(R0 + d) * H_ + 2 * h2) = s;
    }
}

extern "C" void kernel_launch(void* const* d_in, const int* in_sizes, int n_in,
                              void* d_out, int out_size, void* d_ws, size_t ws_size,
                              hipStream_t stream) {
    const float* dec = (const float*)d_in[0];
    const float* enc = (const float*)d_in[1];
    const float* Ww  = (const float*)d_in[2];
    const float* Wb  = (const float*)d_in[3];
    const float* Vw  = (const float*)d_in[4];
    float* out = (float*)d_out;

    prep_kernel<<<dim3(TENC / 32, H_ / 32, B_ + 1), dim3(32, 8), 0, stream>>>(
        enc, dec, Ww, Wb, Vw);
    fused_kernel<<<dim3(B_ * 128), dim3(1024), 0, stream>>>(out);
}

// Round 18
// 46.844 us; speedup vs baseline: 1.7257x; 1.7257x over previous
//
#include <hip/hip_runtime.h>
#include <math.h>

#define B_    4
#define TDEC  512
#define TENC  1024
#define H_    128
#define DT    4

typedef float f2 __attribute__((ext_vector_type(2)));
typedef float vf4 __attribute__((ext_vector_type(4)));

// exp(2*enc) transposed, fp16-packed: [b][gp:16][e:1024][j:8]
__device__ _Float16 g_ebp[(size_t)B_ * 16 * TENC * 8];   // 1 MB
// fp16 copy of enc in natural layout [b][e][h] (for the context phase)
__device__ _Float16 g_ench[(size_t)B_ * TENC * H_];      // 1 MB
// per (row-tile rt, g): [V4(4), h-major ea d-pairs] = 20 f
__device__ float g_eav[(size_t)B_ * 128 * 32 * 20];      // 1.3 MB
__device__ float g_sv[1];                                // sum(V_w)

struct EAVP { float4 v4; f2 hd[8]; };
union F4 { float4 v; float f[4]; };
union H8 { vf4 v; _Float16 h[8]; };
union H4 { ushort4 u4; _Float16 h[4]; };
union H2 { unsigned int u; _Float16 h[2]; };

static __device__ __forceinline__ f2 bc(float x) { f2 r = {x, x}; return r; }

// z<4: transpose enc -> fp16 exp(2*enc) planes + fp16 enc copy.  z==4: Ea+V pack.
__global__ __launch_bounds__(256) void prep_kernel(const float* __restrict__ enc,
                                                   const float* __restrict__ dec,
                                                   const float* __restrict__ Ww,
                                                   const float* __restrict__ Wb,
                                                   const float* __restrict__ Vw) {
    const int z = blockIdx.z;
    const int tx = threadIdx.x, ty = threadIdx.y;
    if (z < B_) {
        __shared__ float tile[32][33];               // [e-local][h-local]
        const int e0 = blockIdx.x * 32, h0 = blockIdx.y * 32, b = z;
        const float* ep = enc + (size_t)b * TENC * H_;
        #pragma unroll
        for (int j = 0; j < 32; j += 8) {
            const float v = ep[(size_t)(e0 + ty + j) * H_ + h0 + tx];
            tile[ty + j][tx] = v;
            g_ench[(size_t)b * TENC * H_ + (size_t)(e0 + ty + j) * H_ + h0 + tx]
                = (_Float16)v;
        }
        __syncthreads();
        const int g = (h0 >> 2) + ty, e = e0 + tx;
        const int gp = g >> 1, hs = g & 1;
        H4 o;
        // clamp below fp16 inf to avoid inf -> NaN in the rcp chain
        o.h[0] = (_Float16)fminf(__expf(2.f * tile[tx][4 * ty + 0]), 60000.f);
        o.h[1] = (_Float16)fminf(__expf(2.f * tile[tx][4 * ty + 1]), 60000.f);
        o.h[2] = (_Float16)fminf(__expf(2.f * tile[tx][4 * ty + 2]), 60000.f);
        o.h[3] = (_Float16)fminf(__expf(2.f * tile[tx][4 * ty + 3]), 60000.f);
        *(ushort4*)&g_ebp[((((size_t)b * 16 + gp) * TENC) + e) * 8 + hs * 4] = o.u4;
    } else {
        // 128 blocks x 16 rows: Ea = exp(2*(dec @ Ww^T + Wb)); pack Ea & V
        __shared__ float ds[16][H_];
        const int t = ty * 32 + tx;
        const int blk = blockIdx.y * 32 + blockIdx.x;      // 0..127
        const int R0 = blk * 16;
        #pragma unroll
        for (int i = 0; i < 8; ++i) {
            const int f = t + 256 * i;
            ds[f >> 7][f & 127] = dec[(size_t)R0 * H_ + f];
        }
        __syncthreads();
        const int k = t & 127, dd = t >> 7;
        const float* wr = Ww + (size_t)k * H_;
        float s[8];
        #pragma unroll
        for (int j = 0; j < 8; ++j) s[j] = 0.f;
        for (int h = 0; h < H_; h += 4) {
            const float4 w4 = *(const float4*)(wr + h);
            #pragma unroll
            for (int j = 0; j < 8; ++j) {
                const float4 d4 = *(const float4*)&ds[dd + 2 * j][h];
                s[j] = fmaf(w4.x, d4.x, s[j]);
                s[j] = fmaf(w4.y, d4.y, s[j]);
                s[j] = fmaf(w4.z, d4.z, s[j]);
                s[j] = fmaf(w4.w, d4.w, s[j]);
            }
        }
        const float wb = Wb[k], vw = Vw[k];
        const int g = k >> 2, jj = k & 3;
        #pragma unroll
        for (int j = 0; j < 8; ++j) {
            const int rl = dd + 2 * j;
            const int R = R0 + rl;
            const float ea = __expf(2.f * (s[j] + wb));
            // h-major, d-minor (packed d-pair math)
            g_eav[((size_t)(R >> 2) * 32 + g) * 20 + 4 + jj * 4 + (R & 3)] = ea;
        }
        if (dd == 0) {
            #pragma unroll
            for (int r = 0; r < 4; ++r)
                g_eav[((size_t)((R0 >> 2) + r) * 32 + g) * 20 + jj] = vw;
        }
        if (blk == 0) {
            __shared__ float svp[2];
            if (t < 128) {
                float x = vw;
                #pragma unroll
                for (int off = 32; off; off >>= 1) x += __shfl_xor(x, off);
                if ((t & 63) == 0) svp[t >> 6] = x;
            }
            __syncthreads();
            if (t == 0) g_sv[0] = svp[0] + svp[1];
        }
    }
}

// Packed 4-h fraction combine over a d-pair; one VOP3P op per step, 2 rcp.
__device__ __forceinline__ f2 term4p(f2 p0, f2 p1, f2 p2, f2 p3,
                                     const float4 v4, f2 acc) {
    const f2 q01 = p0 * p1, q23 = p2 * p3;
    const f2 a   = __builtin_elementwise_fma(bc(v4.y), p0, bc(v4.x) * p1);
    const f2 bq  = __builtin_elementwise_fma(bc(v4.w), p2, bc(v4.z) * p3);
    const f2 num = __builtin_elementwise_fma(bq, q01, a * q23);
    const f2 den = q01 * q23;
    f2 r;
    r.x = __builtin_amdgcn_rcpf(den.x);
    r.y = __builtin_amdgcn_rcpf(den.y);
    return __builtin_elementwise_fma(num, r, acc);
}

#define DALLP(S, t0, t1, t2, t3) do {                                          \
    const f2 one2 = {1.f, 1.f};                                                \
    f2 pA0 = __builtin_elementwise_fma(S.hd[0], bc(t0), one2);                 \
    f2 pB0 = __builtin_elementwise_fma(S.hd[1], bc(t0), one2);                 \
    f2 pA1 = __builtin_elementwise_fma(S.hd[2], bc(t1), one2);                 \
    f2 pB1 = __builtin_elementwise_fma(S.hd[3], bc(t1), one2);                 \
    f2 pA2 = __builtin_elementwise_fma(S.hd[4], bc(t2), one2);                 \
    f2 pB2 = __builtin_elementwise_fma(S.hd[5], bc(t2), one2);                 \
    f2 pA3 = __builtin_elementwise_fma(S.hd[6], bc(t3), one2);                 \
    f2 pB3 = __builtin_elementwise_fma(S.hd[7], bc(t3), one2);                 \
    acc01 = term4p(pA0, pA1, pA2, pA3, S.v4, acc01);                           \
    acc23 = term4p(pB0, pB1, pB2, pB3, S.v4, acc23);                           \
} while (0)

// asm te load: cannot be sunk by the scheduler; ring depth 2, counted waits.
// SOUND: phase 1's only VMEM ops are these (EAV is in LDS -> lgkm counter).
#define GLOAD(dst, ptr) \
    asm volatile("global_load_dwordx4 %0, %1, off" : "=&v"(dst) : "v"(ptr))

// One phase-1 step: EAV ds_reads issued BEFORE the vmcnt wait (their latency
// hides under it); sched_barrier(0) pins the te use after the wait (rule #18).
#define P1ITER(GP, RCUR, CNT) do {                                             \
    const EAVP A  = *(const EAVP*)(evbuf + (2 * (GP) + 0) * 20);               \
    const EAVP Bv = *(const EAVP*)(evbuf + (2 * (GP) + 1) * 20);               \
    asm volatile("s_waitcnt vmcnt(" #CNT ")" ::: "memory");                    \
    __builtin_amdgcn_sched_barrier(0);                                         \
    H8 r; r.v = RCUR;                                                          \
    const float t0 = (float)r.h[0], t1 = (float)r.h[1];                        \
    const float t2 = (float)r.h[2], t3 = (float)r.h[3];                        \
    const float t4 = (float)r.h[4], t5 = (float)r.h[5];                        \
    const float t6 = (float)r.h[6], t7 = (float)r.h[7];                        \
    if ((GP) + 2 < 16) { GLOAD(RCUR, pcur); pcur += TENC * 8; }                \
    DALLP(A,  t0, t1, t2, t3);                                                 \
    DALLP(Bv, t4, t5, t6, t7);                                                 \
} while (0)

// Fused: score + softmax(sum-only) + context + write.  Block = 1 row-tile
// (4 rows), 1024 threads (thread owns 1 e); grid 512, XCD-swizzled.
__global__ __launch_bounds__(1024) void fused_kernel(float* __restrict__ out) {
    __shared__ float sc[DT][TENC];          // p = exp(score)      (16 KB)
    __shared__ f2 part[16][DT][64];         // context partials    (32 KB)
    __shared__ float wsum[16][DT];
    __shared__ float rsum[DT];
    __shared__ __align__(16) float evbuf[640];   // EAV pack for this rt (2.5 KB)

    const int t = threadIdx.x;
    // XCD-locality swizzle: XCD x (= bid%8) gets contiguous row-tiles
    const int bid = blockIdx.x;
    const int rt = (bid & 7) * 64 + (bid >> 3);
    const int b = rt >> 7;
    const int R0 = rt * DT;
    const _Float16* gte = g_ebp + (size_t)b * 16 * TENC * 8 + (size_t)t * 8;

    // Stage EAV to LDS (coalesced); the ds_write forces this wave's staging
    // load to drain, so after the barrier only OUR asm loads touch vmcnt.
    if (t < 640) evbuf[t] = g_eav[(size_t)rt * 640 + t];
    __syncthreads();

    // --- Phase 1: scores; asm te ring depth 2, counted vmcnt ---
    f2 acc01 = {0.f, 0.f}, acc23 = {0.f, 0.f};
    vf4 rA, rB;
    GLOAD(rA, gte + 0 * (TENC * 8));
    GLOAD(rB, gte + 1 * (TENC * 8));
    const _Float16* pcur = gte + 2 * (TENC * 8);

    P1ITER(0,  rA, 1);  P1ITER(1,  rB, 1);
    P1ITER(2,  rA, 1);  P1ITER(3,  rB, 1);
    P1ITER(4,  rA, 1);  P1ITER(5,  rB, 1);
    P1ITER(6,  rA, 1);  P1ITER(7,  rB, 1);
    P1ITER(8,  rA, 1);  P1ITER(9,  rB, 1);
    P1ITER(10, rA, 1);  P1ITER(11, rB, 1);
    P1ITER(12, rA, 1);  P1ITER(13, rB, 1);
    P1ITER(14, rA, 1);  P1ITER(15, rB, 0);

    // --- Phase 2: p = exp(score); stash + per-wave partial sums ---
    const float sv = g_sv[0];
    const float q0 = __expf(fmaf(-2.f, acc01.x, sv));
    const float q1 = __expf(fmaf(-2.f, acc01.y, sv));
    const float q2 = __expf(fmaf(-2.f, acc23.x, sv));
    const float q3 = __expf(fmaf(-2.f, acc23.y, sv));
    sc[0][t] = q0; sc[1][t] = q1; sc[2][t] = q2; sc[3][t] = q3;

    float s0 = q0, s1 = q1, s2 = q2, s3 = q3;
    #pragma unroll
    for (int off = 32; off; off >>= 1) {
        s0 += __shfl_xor(s0, off);
        s1 += __shfl_xor(s1, off);
        s2 += __shfl_xor(s2, off);
        s3 += __shfl_xor(s3, off);
    }
    {
        const int w = t >> 6, lane = t & 63;
        if (lane == 0) { wsum[w][0] = s0; wsum[w][1] = s1; wsum[w][2] = s2; wsum[w][3] = s3; }
    }
    __syncthreads();
    if (t < 64) {                            // lane = w'*4 + d
        float x = wsum[t >> 2][t & 3];
        #pragma unroll
        for (int off = 4; off < 64; off <<= 1) x += __shfl_xor(x, off);
        if (t < 4) rsum[t] = x;
    }

    // --- Phase 3: context partials from fp16 enc; packed (x,y) h-pair math ---
    {
        const int q = t >> 6, h2 = t & 63;
        const _Float16* eb = g_ench + (size_t)b * TENC * H_ + 2 * h2;
        f2 a0 = {0.f, 0.f}, a1 = {0.f, 0.f}, a2 = {0.f, 0.f}, a3 = {0.f, 0.f};
        const int e0 = q * 64;
        for (int e = e0; e < e0 + 64; e += 4) {
            F4 u0, u1, u2, u3;
            u0.v = *(const float4*)&sc[0][e];
            u1.v = *(const float4*)&sc[1][e];
            u2.v = *(const float4*)&sc[2][e];
            u3.v = *(const float4*)&sc[3][e];
            #pragma unroll
            for (int j = 0; j < 4; ++j) {
                H2 hv; hv.u = *(const unsigned int*)(eb + (size_t)(e + j) * H_);
                f2 ev; ev.x = (float)hv.h[0]; ev.y = (float)hv.h[1];
                a0 = __builtin_elementwise_fma(bc(u0.f[j]), ev, a0);
                a1 = __builtin_elementwise_fma(bc(u1.f[j]), ev, a1);
                a2 = __builtin_elementwise_fma(bc(u2.f[j]), ev, a2);
                a3 = __builtin_elementwise_fma(bc(u3.f[j]), ev, a3);
            }
        }
        part[q][0][h2] = a0; part[q][1][h2] = a1;
        part[q][2][h2] = a2; part[q][3][h2] = a3;
    }
    __syncthreads();

    // --- Phase 4: merge 16 slices, divide, write ---
    if (t < 256) {
        const int d = t >> 6, h2 = t & 63;
        f2 s = {0.f, 0.f};
        #pragma unroll
        for (int q = 0; q < 16; ++q) s += part[q][d][h2];
        const float rinv = __builtin_amdgcn_rcpf(rsum[d]);
        s *= bc(rinv);
        *(f2*)(out + (size_t)(R0 + d) * H_ + 2 * h2) = s;
    }
}

extern "C" void kernel_launch(void* const* d_in, const int* in_sizes, int n_in,
                              void* d_out, int out_size, void* d_ws, size_t ws_size,
                              hipStream_t stream) {
    const float* dec = (const float*)d_in[0];
    const float* enc = (const float*)d_in[1];
    const float* Ww  = (const float*)d_in[2];
    const float* Wb  = (const float*)d_in[3];
    const float* Vw  = (const float*)d_in[4];
    float* out = (float*)d_out;

    prep_kernel<<<dim3(TENC / 32, H_ / 32, B_ + 1), dim3(32, 8), 0, stream>>>(
        enc, dec, Ww, Wb, Vw);
    fused_kernel<<<dim3(B_ * 128), dim3(1024), 0, stream>>>(out);
}